// Round 1
// baseline (215.369 us; speedup 1.0000x reference)
//
#include <hip/hip_runtime.h>
#include <stdint.h>

typedef unsigned short u16;
typedef __attribute__((ext_vector_type(8))) short bfrag8;       // 8 x bf16 (MFMA operand)
typedef __attribute__((ext_vector_type(4))) float f32x4;        // MFMA accumulator
typedef __attribute__((ext_vector_type(8))) unsigned short u16x8;
typedef __attribute__((ext_vector_type(4))) unsigned short u16x4;

__device__ __forceinline__ u16 f2bf(float f) {
  union { float f; uint32_t u; } v; v.f = f;
  return (u16)((v.u + 0x7FFFu + ((v.u >> 16) & 1u)) >> 16);   // RNE
}

// ---------------- fp32 -> bf16 convert ----------------
__global__ void cvt_kernel(const float* __restrict__ in, u16* __restrict__ out, int n4) {
  int i = blockIdx.x * blockDim.x + threadIdx.x;
  if (i >= n4) return;
  float4 v = reinterpret_cast<const float4*>(in)[i];
  u16x4 o;
  o[0] = f2bf(v.x); o[1] = f2bf(v.y); o[2] = f2bf(v.z); o[3] = f2bf(v.w);
  reinterpret_cast<u16x4*>(out)[i] = o;
}

// ---------------- NT GEMM: C = A(M,K) @ W(N,K)^T + bias, M=4096,N=1024,K=1024 ----------------
struct Gemm3 {
  const u16* A[3];
  const u16* W[3];
  const float* bias[3];
  void* C[3];
};

template<int OUT_F32>
__global__ __launch_bounds__(256, 2) void gemm_nt_bias(Gemm3 g) {
  constexpr int K = 1024, N = 1024;
  constexpr int BK = 32, LDT = BK + 8;   // +8 bf16 pad -> 80B row stride, conflict-free b128 reads
  __shared__ u16 As[128 * LDT];
  __shared__ u16 Bs[128 * LDT];
  const int z = blockIdx.z;
  const u16* __restrict__ A = g.A[z];
  const u16* __restrict__ W = g.W[z];
  const float* __restrict__ bias = g.bias[z];
  const int tid = threadIdx.x;
  const int lane = tid & 63;
  const int lr = lane & 15, lg = lane >> 4;
  const int wave = tid >> 6;
  const int wr = (wave >> 1) * 64, wc = (wave & 1) * 64;  // 2x2 wave grid, 64x64 each
  const int bm = blockIdx.x * 128, bn = blockIdx.y * 128;

  f32x4 acc[4][4] = {};

  for (int k0 = 0; k0 < K; k0 += BK) {
    // stage 128x32 A-tile and B-tile: 512 units of 16B, 2 per thread
#pragma unroll
    for (int i = 0; i < 2; i++) {
      int u = tid + 256 * i;
      int row = u >> 2, kg = (u & 3) * 8;
      *(u16x8*)&As[row * LDT + kg] = *(const u16x8*)(A + (size_t)(bm + row) * K + k0 + kg);
      *(u16x8*)&Bs[row * LDT + kg] = *(const u16x8*)(W + (size_t)(bn + row) * K + k0 + kg);
    }
    __syncthreads();
    bfrag8 af[4], bf[4];
#pragma unroll
    for (int mi = 0; mi < 4; mi++)
      af[mi] = *(const bfrag8*)&As[(wr + mi * 16 + lr) * LDT + lg * 8];
#pragma unroll
    for (int ni = 0; ni < 4; ni++)
      bf[ni] = *(const bfrag8*)&Bs[(wc + ni * 16 + lr) * LDT + lg * 8];
#pragma unroll
    for (int mi = 0; mi < 4; mi++)
#pragma unroll
      for (int ni = 0; ni < 4; ni++)
        acc[mi][ni] = __builtin_amdgcn_mfma_f32_16x16x32_bf16(af[mi], bf[ni], acc[mi][ni], 0, 0, 0);
    __syncthreads();
  }

  // epilogue: C/D layout col=lane&15, row=(lane>>4)*4+r
  const int col0 = bn + wc + lr;
#pragma unroll
  for (int ni = 0; ni < 4; ni++) {
    int col = col0 + ni * 16;
    float bv = bias[col];
#pragma unroll
    for (int mi = 0; mi < 4; mi++) {
      int row = bm + wr + mi * 16 + lg * 4;
#pragma unroll
      for (int r = 0; r < 4; r++) {
        float v = acc[mi][ni][r] + bv;
        if (OUT_F32)
          ((float*)g.C[z])[(size_t)(row + r) * N + col] = v;
        else
          ((u16*)g.C[z])[(size_t)(row + r) * N + col] = f2bf(v);
      }
    }
  }
}

// ---------------- causal flash attention per (b,h): Q,K,V contiguous (2048,64) ----------------
// grid: x = q-tile (16), y = bh (32). 4 waves; wave w owns q rows [qt*128+w*32, +32).
__global__ __launch_bounds__(256, 2) void attn_kernel(
    const u16* __restrict__ Qp, const u16* __restrict__ Kp,
    const u16* __restrict__ Vp, u16* __restrict__ X)
{
  __shared__ u16 Ks[128][72];      // K tile, padded (144B stride)
  __shared__ u16 Vt[64][136];      // V tile transposed: Vt[d][kpos], padded (272B stride)
  __shared__ u16 Ps[4][32][136];   // per-wave P tile (32 q-rows x 128 kpos), padded

  const int qt = blockIdx.x;
  const int bh = blockIdx.y;
  const size_t base = (size_t)bh * (2048 * 64);
  const u16* __restrict__ Qb = Qp + base;
  const u16* __restrict__ Kb = Kp + base;
  const u16* __restrict__ Vb = Vp + base;
  const int tid = threadIdx.x, lane = tid & 63, w = tid >> 6;
  const int lr = lane & 15, lg = lane >> 4;

  // Q fragments in registers: rows qt*128 + w*32 + mi*16 + lr, d = ds*32 + lg*8
  bfrag8 qf[2][2];
#pragma unroll
  for (int mi = 0; mi < 2; mi++)
#pragma unroll
    for (int ds = 0; ds < 2; ds++)
      qf[mi][ds] = *(const bfrag8*)(Qb + (size_t)(qt * 128 + w * 32 + mi * 16 + lr) * 64 + ds * 32 + lg * 8);

  f32x4 oacc[2][4] = {};
  float m_run[2][4], l_run[2][4];
#pragma unroll
  for (int mi = 0; mi < 2; mi++)
#pragma unroll
    for (int r = 0; r < 4; r++) { m_run[mi][r] = -INFINITY; l_run[mi][r] = 0.f; }

  const float SCALE = 0.03125f;  // 1/sqrt(1024)

  for (int kt = 0; kt <= qt; kt++) {
    // stage K tile (row-major) and V tile (transposed)
#pragma unroll
    for (int i = 0; i < 4; i++) {
      int u = tid + 256 * i;
      int row = u >> 3, dg = (u & 7) * 8;
      *(u16x8*)&Ks[row][dg] = *(const u16x8*)(Kb + (size_t)(kt * 128 + row) * 64 + dg);
      u16x8 vv = *(const u16x8*)(Vb + (size_t)(kt * 128 + row) * 64 + dg);
#pragma unroll
      for (int j = 0; j < 8; j++) Vt[dg + j][row] = vv[j];
    }
    __syncthreads();

    // S = Q K^T  (per wave: 32 q-rows x 128 k-cols)
    f32x4 sacc[2][8];
#pragma unroll
    for (int mi = 0; mi < 2; mi++)
#pragma unroll
      for (int kf = 0; kf < 8; kf++) sacc[mi][kf] = (f32x4){0.f, 0.f, 0.f, 0.f};
#pragma unroll
    for (int kf = 0; kf < 8; kf++) {
      bfrag8 kb0 = *(const bfrag8*)&Ks[kf * 16 + lr][lg * 8];
      bfrag8 kb1 = *(const bfrag8*)&Ks[kf * 16 + lr][32 + lg * 8];
#pragma unroll
      for (int mi = 0; mi < 2; mi++) {
        sacc[mi][kf] = __builtin_amdgcn_mfma_f32_16x16x32_bf16(qf[mi][0], kb0, sacc[mi][kf], 0, 0, 0);
        sacc[mi][kf] = __builtin_amdgcn_mfma_f32_16x16x32_bf16(qf[mi][1], kb1, sacc[mi][kf], 0, 0, 0);
      }
    }

    // scale + causal mask (only the diagonal tile has masked entries)
    const bool diag = (kt == qt);
#pragma unroll
    for (int mi = 0; mi < 2; mi++)
#pragma unroll
      for (int kf = 0; kf < 8; kf++)
#pragma unroll
        for (int r = 0; r < 4; r++) {
          float x = sacc[mi][kf][r] * SCALE;
          if (diag) {
            int qg = w * 32 + mi * 16 + lg * 4 + r;
            int kg = kf * 16 + lr;
            if (kg > qg) x = -INFINITY;
          }
          sacc[mi][kf][r] = x;
        }

    // online softmax update per q-row; P -> LDS (bf16)
#pragma unroll
    for (int mi = 0; mi < 2; mi++) {
#pragma unroll
      for (int r = 0; r < 4; r++) {
        float mt = sacc[mi][0][r];
#pragma unroll
        for (int kf = 1; kf < 8; kf++) mt = fmaxf(mt, sacc[mi][kf][r]);
        mt = fmaxf(mt, __shfl_xor(mt, 1));
        mt = fmaxf(mt, __shfl_xor(mt, 2));
        mt = fmaxf(mt, __shfl_xor(mt, 4));
        mt = fmaxf(mt, __shfl_xor(mt, 8));
        float mnew = fmaxf(m_run[mi][r], mt);
        float corr = __expf(m_run[mi][r] - mnew);   // first tile: exp(-inf)=0
        m_run[mi][r] = mnew;
        l_run[mi][r] *= corr;
#pragma unroll
        for (int df = 0; df < 4; df++) oacc[mi][df][r] *= corr;
        float rs = 0.f;
#pragma unroll
        for (int kf = 0; kf < 8; kf++) {
          float p = __expf(sacc[mi][kf][r] - mnew);  // masked: exp(-inf)=0
          rs += p;
          Ps[w][mi * 16 + lg * 4 + r][kf * 16 + lr] = f2bf(p);
        }
        rs += __shfl_xor(rs, 1);
        rs += __shfl_xor(rs, 2);
        rs += __shfl_xor(rs, 4);
        rs += __shfl_xor(rs, 8);
        l_run[mi][r] += rs;
      }
    }
    __syncthreads();   // P visible (and keeps waves together before Vt reads)

    // O += P V : A-frag from Ps (row=q, k contiguous), B-frag from Vt (row=d, k contiguous)
#pragma unroll
    for (int mi = 0; mi < 2; mi++) {
#pragma unroll
      for (int ks = 0; ks < 4; ks++) {
        bfrag8 pa = *(const bfrag8*)&Ps[w][mi * 16 + lr][ks * 32 + lg * 8];
#pragma unroll
        for (int df = 0; df < 4; df++) {
          bfrag8 vf = *(const bfrag8*)&Vt[df * 16 + lr][ks * 32 + lg * 8];
          oacc[mi][df] = __builtin_amdgcn_mfma_f32_16x16x32_bf16(pa, vf, oacc[mi][df], 0, 0, 0);
        }
      }
    }
    __syncthreads();   // before next tile overwrites Ks/Vt
  }

  // normalize and write X (head-contiguous layout == raw-view merge)
#pragma unroll
  for (int mi = 0; mi < 2; mi++) {
#pragma unroll
    for (int r = 0; r < 4; r++) {
      float inv = 1.0f / l_run[mi][r];
      int row = qt * 128 + w * 32 + mi * 16 + lg * 4 + r;
#pragma unroll
      for (int df = 0; df < 4; df++)
        X[base + (size_t)row * 64 + df * 16 + lr] = f2bf(oacc[mi][df][r] * inv);
    }
  }
}

extern "C" void kernel_launch(void* const* d_in, const int* in_sizes, int n_in,
                              void* d_out, int out_size, void* d_ws, size_t ws_size,
                              hipStream_t stream) {
  const float* key   = (const float*)d_in[0];
  const float* query = (const float*)d_in[1];
  const float* value = (const float*)d_in[2];
  const float* Wq = (const float*)d_in[4];
  const float* bq = (const float*)d_in[5];
  const float* Wk = (const float*)d_in[6];
  const float* bk = (const float*)d_in[7];
  const float* Wv = (const float*)d_in[8];
  const float* bv = (const float*)d_in[9];
  const float* Wo = (const float*)d_in[10];
  const float* bo = (const float*)d_in[11];

  u16* ws = (u16*)d_ws;
  const size_t MD = 4096ull * 1024ull;          // 4M elems
  u16* qb  = ws;                                 // query bf16
  u16* kb  = ws + MD;                            // key bf16
  u16* vbf = ws + 2 * MD;                        // value bf16
  u16* Qp  = ws + 3 * MD;                        // projected Q
  u16* Kp  = ws + 4 * MD;
  u16* Vp  = ws + 5 * MD;
  u16* Xb  = ws + 6 * MD;                        // attention output
  u16* wqb = ws + 7 * MD;                        // weights bf16 (1M each)
  u16* wkb = wqb + 1024 * 1024;
  u16* wvb = wkb + 1024 * 1024;
  u16* wob = wvb + 1024 * 1024;

  cvt_kernel<<<4096, 256, 0, stream>>>(query, qb, 1048576);
  cvt_kernel<<<4096, 256, 0, stream>>>(key,   kb, 1048576);
  cvt_kernel<<<4096, 256, 0, stream>>>(value, vbf, 1048576);
  cvt_kernel<<<1024, 256, 0, stream>>>(Wq, wqb, 262144);
  cvt_kernel<<<1024, 256, 0, stream>>>(Wk, wkb, 262144);
  cvt_kernel<<<1024, 256, 0, stream>>>(Wv, wvb, 262144);
  cvt_kernel<<<1024, 256, 0, stream>>>(Wo, wob, 262144);

  Gemm3 g1;
  g1.A[0] = qb;  g1.A[1] = kb;  g1.A[2] = vbf;
  g1.W[0] = wqb; g1.W[1] = wkb; g1.W[2] = wvb;
  g1.bias[0] = bq; g1.bias[1] = bk; g1.bias[2] = bv;
  g1.C[0] = Qp; g1.C[1] = Kp; g1.C[2] = Vp;
  gemm_nt_bias<0><<<dim3(32, 8, 3), 256, 0, stream>>>(g1);

  attn_kernel<<<dim3(16, 32), 256, 0, stream>>>(Qp, Kp, Vp, Xb);

  Gemm3 g2;
  g2.A[0] = Xb; g2.W[0] = wob; g2.bias[0] = bo; g2.C[0] = d_out;
  g2.A[1] = g2.A[2] = nullptr; g2.W[1] = g2.W[2] = nullptr;
  g2.bias[1] = g2.bias[2] = nullptr; g2.C[1] = g2.C[2] = nullptr;
  gemm_nt_bias<1><<<dim3(32, 8, 1), 256, 0, stream>>>(g2);
}